// Round 3
// baseline (17.505 us; speedup 1.0000x reference)
//
#include <hip/hip_runtime.h>

// ANI radial symmetry function:
//   out[b,a,r] = sum_n exp(-eta[r]*(d-rss[r])^2) * cutoff(d) * mask,  d = r_ij[b,a,n]
//   cutoff(d) = 0.5*(cos(pi*d/3)+1) for d<3 else 0
// Shapes: r_ij/mask [16,2048,96] f32, etas/rss [16] f32, out [16,2048,16] f32.
//
// v2: zero-skip compaction. ~44% of entries have w = cutoff*mask == 0
// (mask==0 or d>=3); skipping them is exact. Phase 1: each 16-lane group
// loads its row (coalesced float2), computes w once per neighbor, and
// ballot/popcount-compacts the (d,w) pairs with w!=0 into an LDS pool
// (padded to a multiple of 4 with zero pairs). Phase 2: thread
// (row=tid>>4, r=tid&15) holds Horner constants for ONE radial basis and
// walks the ~54-entry compacted list via broadcast float4 LDS reads
// (conflict-free), 4 accumulators for ILP. Cuts trans-pipe (v_exp_f32)
// and inner VALU work ~40% at identical global traffic.

#define NN    96
#define RR    16
#define NROWS 16
#define SLOTS 104   // 96 + 4 pad slots, rounded; row stride 832B (16B-aligned)

__global__ __launch_bounds__(256) void ani_radial_kernel(
    const float* __restrict__ r_ij,
    const float* __restrict__ mask,
    const float* __restrict__ etas,
    const float* __restrict__ rss,
    float* __restrict__ out)
{
    __shared__ float2 pool[NROWS * SLOTS];
    __shared__ int    cntLds[NROWS];

    const int tid  = threadIdx.x;
    const int rowL = tid >> 4;          // 0..15: row within block
    const int t    = tid & 15;          // lane within 16-lane group
    const int g    = (tid >> 4) & 3;    // group within the 64-lane wave
    const long long row = (long long)blockIdx.x * NROWS + rowL;

    const float* __restrict__ pr = r_ij + row * NN;
    const float* __restrict__ pm = mask + row * NN;

    // ---- Phase 1: load row, compute w = cutoff*mask, compact (d,w!=0) ----
    float dd[6], mm[6], ww[6];
    #pragma unroll
    for (int j = 0; j < 3; ++j) {
        const int n = 32 * j + 2 * t;   // 16-lane group reads 128B contiguous
        const float2 d2 = *reinterpret_cast<const float2*>(pr + n);
        const float2 m2 = *reinterpret_cast<const float2*>(pm + n);
        dd[2*j] = d2.x; dd[2*j+1] = d2.y;
        mm[2*j] = m2.x; mm[2*j+1] = m2.y;
    }
    #pragma unroll
    for (int u = 0; u < 6; ++u) {
        const float d = dd[u];
        // v_cos takes revolutions: cos(pi*d/3) = cos(2*pi*(d/6)), d/6 in [0,0.67)
        const float c = __builtin_amdgcn_cosf(d * 0.16666666666666666f);
        const float w = __builtin_fmaf(0.5f, c, 0.5f) * mm[u];
        ww[u] = (d < 3.0f) ? w : 0.0f;
    }

    float2* __restrict__ rowPool = pool + rowL * SLOTS;
    int base = 0;
    #pragma unroll
    for (int u = 0; u < 6; ++u) {
        const bool p = (ww[u] != 0.0f);
        const unsigned long long bal = __ballot(p);
        const unsigned bits = (unsigned)((bal >> (g * 16)) & 0xffffull);
        const int before = __popc(bits & ((1u << t) - 1u));
        if (p) rowPool[base + before] = make_float2(dd[u], ww[u]);
        base += __popc(bits);
    }
    // pad to multiple of 4 with zero-weight entries (contribute exactly 0)
    if (t < 4) rowPool[base + t] = make_float2(0.0f, 0.0f);
    if (t == 0) cntLds[rowL] = (base + 3) & ~3;
    __syncthreads();

    // ---- Phase 2: thread (rowL, r=t) sums its RBF over the compacted list ----
    const float LOG2E = 1.4426950408889634f;
    const float eta = etas[t];
    const float rs  = rss[t];
    const float k  = -eta * LOG2E;          // exponent in log2 domain
    const float pb = -2.0f * k * rs;        // k*(d-rs)^2 = k*d^2 + pb*d + pc
    const float pc = k * rs * rs;

    const int n = cntLds[rowL];
    const float4* __restrict__ q = reinterpret_cast<const float4*>(rowPool);

    float a0 = 0.0f, a1 = 0.0f, a2 = 0.0f, a3 = 0.0f;
    for (int i = 0; i < n; i += 4) {
        const float4 x = q[(i >> 1)];       // pairs i, i+1   (broadcast read)
        const float4 y = q[(i >> 1) + 1];   // pairs i+2, i+3
        a0 = __builtin_fmaf(
            __builtin_amdgcn_exp2f(__builtin_fmaf(__builtin_fmaf(k, x.x, pb), x.x, pc)),
            x.y, a0);
        a1 = __builtin_fmaf(
            __builtin_amdgcn_exp2f(__builtin_fmaf(__builtin_fmaf(k, x.z, pb), x.z, pc)),
            x.w, a1);
        a2 = __builtin_fmaf(
            __builtin_amdgcn_exp2f(__builtin_fmaf(__builtin_fmaf(k, y.x, pb), y.x, pc)),
            y.y, a2);
        a3 = __builtin_fmaf(
            __builtin_amdgcn_exp2f(__builtin_fmaf(__builtin_fmaf(k, y.z, pb), y.z, pc)),
            y.w, a3);
    }

    out[row * RR + t] = (a0 + a1) + (a2 + a3);
}

extern "C" void kernel_launch(void* const* d_in, const int* in_sizes, int n_in,
                              void* d_out, int out_size, void* d_ws, size_t ws_size,
                              hipStream_t stream) {
    const float* r_ij = (const float*)d_in[0];
    const float* mask = (const float*)d_in[1];
    const float* etas = (const float*)d_in[2];
    const float* rss  = (const float*)d_in[3];
    float* out = (float*)d_out;

    const int totalRows = in_sizes[0] / NN;  // B*A = 32768
    const int grid = totalRows / NROWS;      // 2048 blocks of 256 threads

    ani_radial_kernel<<<grid, 256, 0, stream>>>(r_ij, mask, etas, rss, out);
}

// Round 4
// 14.914 us; speedup vs baseline: 1.1737x; 1.1737x over previous
//
#include <hip/hip_runtime.h>

// ANI radial symmetry function:
//   out[b,a,r] = sum_n exp(-eta[r]*(d-rss[r])^2) * cutoff(d) * mask,  d = r_ij[b,a,n]
//   cutoff(d) = 0.5*(cos(pi*d/3)+1) for d<3 else 0
// Shapes: r_ij/mask [16,2048,96] f32, etas/rss [16] f32, out [16,2048,16] f32.
//
// v3: latency-minimal. No LDS, no barrier. Thread (row=tid>>4, t=tid&15)
// owns 6 neighbors loaded as one float4 (n=4t..4t+3, 256B contiguous per
// 16-lane group) + one float2 (n=64+2t, 128B contiguous). Evaluates all 16
// RBFs per neighbor (Horner in log2 domain, v_exp_f32 direct), 4-stage
// halving butterfly over the 16-lane group -> lane t holds the r=t sum ->
// coalesced dword store. Hypothesis under test: measured floor = ~4.3us
// HBM-bound kernel + ~10us fixed graph-replay overhead.

#define NN 96
#define RR 16

__global__ __launch_bounds__(256) void ani_radial_kernel(
    const float* __restrict__ r_ij,
    const float* __restrict__ mask,
    const float* __restrict__ etas,
    const float* __restrict__ rss,
    float* __restrict__ out)
{
    const int tid  = threadIdx.x;
    const int rowL = tid >> 4;   // 16 rows per block
    const int t    = tid & 15;   // lane within 16-lane group
    const long long row = (long long)blockIdx.x * 16 + rowL;

    const float* __restrict__ pr = r_ij + row * NN;
    const float* __restrict__ pm = mask + row * NN;

    // Issue all 4 global loads up front (independent -> overlapped).
    const float4 d4 = *reinterpret_cast<const float4*>(pr + 4 * t);
    const float2 d2 = *reinterpret_cast<const float2*>(pr + 64 + 2 * t);
    const float4 m4 = *reinterpret_cast<const float4*>(pm + 4 * t);
    const float2 m2 = *reinterpret_cast<const float2*>(pm + 64 + 2 * t);

    // Per-r Horner constants in log2 domain:
    //   -eta*(d-rs)^2 * log2e = k*d^2 + pb*d + pc
    const float LOG2E = 1.4426950408889634f;
    float k[RR], pb[RR], pc[RR];
    #pragma unroll
    for (int r = 0; r < RR; ++r) {
        const float eta = etas[r];
        const float rs  = rss[r];
        k[r]  = -eta * LOG2E;
        pb[r] = -2.0f * k[r] * rs;
        pc[r] = k[r] * rs * rs;
    }

    const float dd[6] = {d4.x, d4.y, d4.z, d4.w, d2.x, d2.y};
    const float mm[6] = {m4.x, m4.y, m4.z, m4.w, m2.x, m2.y};

    float acc[RR];
    #pragma unroll
    for (int r = 0; r < RR; ++r) acc[r] = 0.0f;

    #pragma unroll
    for (int u = 0; u < 6; ++u) {
        const float d = dd[u];
        // v_cos takes revolutions: cos(pi*d/3)=cos(2*pi*(d/6)), d/6 in [0,0.67)
        const float c = __builtin_amdgcn_cosf(d * 0.16666666666666666f);
        float w = __builtin_fmaf(0.5f, c, 0.5f);
        w = (d < 3.0f) ? w * mm[u] : 0.0f;
        #pragma unroll
        for (int r = 0; r < RR; ++r) {
            const float e = __builtin_fmaf(__builtin_fmaf(k[r], d, pb[r]), d, pc[r]);
            acc[r] = __builtin_fmaf(__builtin_amdgcn_exp2f(e), w, acc[r]);
        }
    }

    // Halving butterfly transpose-reduce over the 16-lane group.
#define RSTAGE(S, NV)                                                   \
    {                                                                   \
        const bool hi = (t & (S)) != 0;                                 \
        _Pragma("unroll")                                               \
        for (int i = 0; i < (NV) / 2; ++i) {                            \
            const float send = hi ? acc[i] : acc[i + (NV) / 2];         \
            const float recv = __shfl_xor(send, (S), 16);               \
            const float keep = hi ? acc[i + (NV) / 2] : acc[i];         \
            acc[i] = keep + recv;                                       \
        }                                                               \
    }
    RSTAGE(8, 16)
    RSTAGE(4, 8)
    RSTAGE(2, 4)
    RSTAGE(1, 2)
#undef RSTAGE

    out[row * RR + t] = acc[0];
}

extern "C" void kernel_launch(void* const* d_in, const int* in_sizes, int n_in,
                              void* d_out, int out_size, void* d_ws, size_t ws_size,
                              hipStream_t stream) {
    const float* r_ij = (const float*)d_in[0];
    const float* mask = (const float*)d_in[1];
    const float* etas = (const float*)d_in[2];
    const float* rss  = (const float*)d_in[3];
    float* out = (float*)d_out;

    const int totalRows = in_sizes[0] / NN;  // B*A = 32768
    const int grid = totalRows / 16;         // 2048 blocks of 256 threads

    ani_radial_kernel<<<grid, 256, 0, stream>>>(r_ij, mask, etas, rss, out);
}